// Round 2
// 259.560 us; speedup vs baseline: 1.0326x; 1.0326x over previous
//
#include <hip/hip_runtime.h>

typedef float v4 __attribute__((ext_vector_type(4)));

#define D_MODEL 1024
#define D_STATE 64
#define CHUNK   256
#define TILE_T  64

// Grid: 1024 blocks = 64 bc-chunks x 16 d-slices (64 d each).
// Block: 256 threads = 4 waves; 4 blocks/CU -> 16 waves/CU (4 waves/SIMD).
// Lane owns 1 d-column x 16 n: quad-lane ng = tid&3 covers n in [ng*16, ng*16+16).
// h[16], a[16] live in VGPRs. B/C broadcast from LDS tiles (8 ds_read_b128/t,
// 4 distinct addrs x 16-lane broadcast each -> 2-way bank aliasing, free).
// y reduction across the 4 n-groups = 2 in-wave shfl_xor. NO per-t barrier:
// barriers only bracket the 64-t B/C staging (8 total vs ~260 before).
__global__ __launch_bounds__(256, 4)
void YvParallelScan_kernel(const float* __restrict__ u,
                           const float* __restrict__ B,
                           const float* __restrict__ C,
                           const float* __restrict__ A_log,
                           float* __restrict__ out) {
    __shared__ v4 sB[TILE_T * 16];   // [tl][n/4]  16 KB
    __shared__ v4 sC[TILE_T * 16];   // 16 KB

    const int bid = blockIdx.x;
    const int bc  = bid >> 4;          // 0..63  (batch*chunk index)
    const int ds  = bid & 15;          // d-slice within D_MODEL
    const int tid = threadIdx.x;
    const int ng  = tid & 3;           // n-group within quad
    const int dq  = tid >> 2;          // 0..63: d within slice
    const int d   = ds * 64 + dq;      // global d
    const int rowbase = bc * CHUNK;

    const v4* Bg = (const v4*)(B + (size_t)rowbase * D_STATE);
    const v4* Cg = (const v4*)(C + (size_t)rowbase * D_STATE);

    float a[16], h[16];
#pragma unroll
    for (int j = 0; j < 16; ++j) {
        const int n = ng * 16 + j;
        a[j] = -__expf(A_log[n * D_MODEL + d]);
        h[j] = 0.f;
    }

    const float* uptr = u + (size_t)rowbase * D_MODEL + d;
    float*       optr = out + (size_t)rowbase * D_MODEL + d;

    // x prefetch, depth 2 (covers HBM latency across 4 resident waves/SIMD)
    float xa = uptr[0];
    float xb = uptr[D_MODEL];

    for (int ti = 0; ti < CHUNK / TILE_T; ++ti) {
        // stage 64-t tile of B,C (coalesced v4 copies; tiny vs 64 t of compute)
#pragma unroll
        for (int k = 0; k < 4; ++k) {
            sB[k * 256 + tid] = Bg[ti * 1024 + k * 256 + tid];
            sC[k * 256 + tid] = Cg[ti * 1024 + k * 256 + tid];
        }
        __syncthreads();

#pragma unroll 4
        for (int tl = 0; tl < TILE_T; ++tl) {
            const int t  = ti * TILE_T + tl;
            const int tp = (t + 2 < CHUNK) ? (t + 2) : (CHUNK - 1);
            const float xn = uptr[(size_t)tp * D_MODEL];

            const float x = xa;
            float acc0 = 0.f, acc1 = 0.f;
#pragma unroll
            for (int jj = 0; jj < 4; ++jj) {
                const v4 b4 = sB[tl * 16 + ng * 4 + jj];   // broadcast ds_read_b128
                const v4 c4 = sC[tl * 16 + ng * 4 + jj];
#pragma unroll
                for (int k = 0; k < 4; ++k) {
                    const int j = jj * 4 + k;
                    h[j] = a[j] * h[j] + b4[k] * x;
                    if (k & 1) acc1 += c4[k] * h[j];       // 2 chains, shorter dep path
                    else       acc0 += c4[k] * h[j];
                }
            }
            float acc = acc0 + acc1;
            // quad butterfly over the 4 n-groups (lanes differ in tid bits 0..1)
            acc += __shfl_xor(acc, 1);
            acc += __shfl_xor(acc, 2);
            if (ng == 0) optr[(size_t)t * D_MODEL] = acc;
            xa = xb; xb = xn;
        }
        __syncthreads();   // all reads of this tile done before restage
    }
}

extern "C" void kernel_launch(void* const* d_in, const int* in_sizes, int n_in,
                              void* d_out, int out_size, void* d_ws, size_t ws_size,
                              hipStream_t stream) {
    const float* u     = (const float*)d_in[0];
    // d_in[1] = delta, unused by the reference forward
    const float* B     = (const float*)d_in[2];
    const float* C     = (const float*)d_in[3];
    const float* A_log = (const float*)d_in[4];
    float* out = (float*)d_out;

    YvParallelScan_kernel<<<1024, 256, 0, stream>>>(u, B, C, A_log, out);
}